// Round 11
// baseline (402.977 us; speedup 1.0000x reference)
//
#include <hip/hip_runtime.h>
#include <hip/hip_bf16.h>

#define NN 50000
#define NE 600000
#define IN_DIM 128
#define HC 128      // H*C
#define NH 4
#define NC 32
#define NEG_SLOPE 0.2f

#define SB 512
#define SNB ((NN + SB - 1) / SB)   // 98 scan blocks

typedef __attribute__((ext_vector_type(8))) short short8;
typedef __attribute__((ext_vector_type(4))) float floatx4;
typedef __attribute__((ext_vector_type(8))) unsigned short ushort8v;

__device__ __forceinline__ float bf2f(unsigned short u) {
    return __uint_as_float(((unsigned)u) << 16);
}
__device__ __forceinline__ unsigned short f2bf(float f) {
    unsigned u = __float_as_uint(f);
    unsigned r = (u + 0x7FFFu + ((u >> 16) & 1u)) >> 16;   // RNE
    return (unsigned short)r;
}

// ---------------- weight pre-transpose: Wt[n][k] = bf16(W[k][n]) ----------------
// grid = OD blocks, 128 threads (k). Writes coalesced; tiny one-off cost.
__global__ void w_transpose(const float* __restrict__ W, unsigned short* __restrict__ Wt, int OD) {
    int n = blockIdx.x;
    int k = threadIdx.x;
    Wt[n * 128 + k] = f2bf(W[(size_t)k * OD + n]);
}

// ============ LDS-free MFMA GEMM: each wave = 32 rows x OD cols, K=128 ============
// A-frag: 16 contiguous bytes of x row (bf16) / converted fp32.
// B-frag: 16 contiguous bytes of pre-transposed Wt[col][k] (L1/L2-resident).
// No LDS, no barriers; occupancy VGPR-bound.
template<typename AT, int OD, int OBF>
__device__ __forceinline__ void gemm_wave(
    const AT* __restrict__ x, const unsigned short* __restrict__ Wt,
    const float* __restrict__ b, void* __restrict__ yv, int n0, int lane) {
    int quad = lane >> 4, l16 = lane & 15;
    floatx4 acc[2][OD / 16];
    #pragma unroll
    for (int i = 0; i < 2; ++i)
        #pragma unroll
        for (int j = 0; j < OD / 16; ++j) acc[i][j] = (floatx4){0.f, 0.f, 0.f, 0.f};

    int r0 = n0 + l16;      if (r0 >= NN) r0 = NN - 1;
    int r1 = n0 + 16 + l16; if (r1 >= NN) r1 = NN - 1;

    #pragma unroll
    for (int ks = 0; ks < 4; ++ks) {
        int kb = ks * 32 + quad * 8;
        short8 a0, a1;
        if constexpr (sizeof(AT) == 4) {
            const float* xr = (const float*)x;
            float4 v0 = *(const float4*)&xr[(size_t)r0 * IN_DIM + kb];
            float4 v1 = *(const float4*)&xr[(size_t)r0 * IN_DIM + kb + 4];
            float4 u0 = *(const float4*)&xr[(size_t)r1 * IN_DIM + kb];
            float4 u1 = *(const float4*)&xr[(size_t)r1 * IN_DIM + kb + 4];
            a0 = (short8){(short)f2bf(v0.x), (short)f2bf(v0.y), (short)f2bf(v0.z), (short)f2bf(v0.w),
                          (short)f2bf(v1.x), (short)f2bf(v1.y), (short)f2bf(v1.z), (short)f2bf(v1.w)};
            a1 = (short8){(short)f2bf(u0.x), (short)f2bf(u0.y), (short)f2bf(u0.z), (short)f2bf(u0.w),
                          (short)f2bf(u1.x), (short)f2bf(u1.y), (short)f2bf(u1.z), (short)f2bf(u1.w)};
        } else {
            a0 = *(const short8*)&((const unsigned short*)x)[(size_t)r0 * IN_DIM + kb];
            a1 = *(const short8*)&((const unsigned short*)x)[(size_t)r1 * IN_DIM + kb];
        }
        #pragma unroll
        for (int tc = 0; tc < OD / 16; ++tc) {
            short8 bf = *(const short8*)&Wt[(size_t)(tc * 16 + l16) * 128 + kb];
            acc[0][tc] = __builtin_amdgcn_mfma_f32_16x16x32_bf16(a0, bf, acc[0][tc], 0, 0, 0);
            acc[1][tc] = __builtin_amdgcn_mfma_f32_16x16x32_bf16(a1, bf, acc[1][tc], 0, 0, 0);
        }
    }

    // epilogue: D row = tr*16 + quad*4 + r, col = tc*16 + l16
    #pragma unroll
    for (int tc = 0; tc < OD / 16; ++tc) {
        float bv = b[tc * 16 + l16];
        #pragma unroll
        for (int tr = 0; tr < 2; ++tr) {
            #pragma unroll
            for (int r = 0; r < 4; ++r) {
                int row = n0 + tr * 16 + quad * 4 + r;
                if (row < NN) {
                    float v = acc[tr][tc][r] + bv;
                    if constexpr (OBF)
                        ((unsigned short*)yv)[(size_t)row * OD + tc * 16 + l16] = f2bf(v);
                    else
                        ((float*)yv)[(size_t)row * OD + tc * 16 + l16] = v;
                }
            }
        }
    }
}

// dual GEMM (l<2): grid.y==0 -> h (bf16), grid.y==1 -> skip (fp32), both OD=128
template<typename AT>
__global__ __launch_bounds__(256) void gemm_dual_lf(
    const AT* __restrict__ x,
    const unsigned short* __restrict__ Wta, const float* __restrict__ ba, unsigned short* __restrict__ ya,
    const unsigned short* __restrict__ Wtb, const float* __restrict__ bb, float* __restrict__ yb) {
    int wid = threadIdx.x >> 6, lane = threadIdx.x & 63;
    int n0 = (blockIdx.x * 4 + wid) * 32;
    if (n0 >= NN) return;
    if (blockIdx.y == 0) gemm_wave<AT, 128, 1>(x, Wta, ba, (void*)ya, n0, lane);
    else                 gemm_wave<AT, 128, 0>(x, Wtb, bb, (void*)yb, n0, lane);
}

template<typename AT, int OD, int OBF>
__global__ __launch_bounds__(256) void gemm_one_lf(
    const AT* __restrict__ x, const unsigned short* __restrict__ Wt,
    const float* __restrict__ b, void* __restrict__ yv) {
    int wid = threadIdx.x >> 6, lane = threadIdx.x & 63;
    int n0 = (blockIdx.x * 4 + wid) * 32;
    if (n0 >= NN) return;
    gemm_wave<AT, OD, OBF>(x, Wt, b, yv, n0, lane);
}

// ---------------- CSR build ----------------
__global__ void hist_deg(const int* __restrict__ dst, int* __restrict__ deg) {
    int e = blockIdx.x * blockDim.x + threadIdx.x;
    if (e < NE) atomicAdd(&deg[dst[e]], 1);
}

__global__ __launch_bounds__(SB) void scan1(const int* __restrict__ deg,
                                            int* __restrict__ partial,
                                            int* __restrict__ blocksum) {
    __shared__ int sh[SB];
    int b = blockIdx.x, t = threadIdx.x;
    int i = b * SB + t;
    int d = (i < NN) ? deg[i] : 0;
    sh[t] = d;
    __syncthreads();
    #pragma unroll
    for (int off = 1; off < SB; off <<= 1) {
        int v = (t >= off) ? sh[t - off] : 0;
        __syncthreads();
        sh[t] += v;
        __syncthreads();
    }
    if (i < NN) partial[i] = sh[t];
    if (t == SB - 1) blocksum[b] = sh[t];
}

__global__ __launch_bounds__(128) void scan2(int* __restrict__ blocksum) {
    __shared__ int sh[128];
    int t = threadIdx.x;
    int v = (t < SNB) ? blocksum[t] : 0;
    sh[t] = v;
    __syncthreads();
    #pragma unroll
    for (int off = 1; off < 128; off <<= 1) {
        int u = (t >= off) ? sh[t - off] : 0;
        __syncthreads();
        sh[t] += u;
        __syncthreads();
    }
    if (t < SNB) blocksum[t] = sh[t] - v;   // exclusive prefix
}

__global__ void scan3(const int* __restrict__ deg, const int* __restrict__ partial,
                      const int* __restrict__ blocksum, int* __restrict__ rowptr,
                      int* __restrict__ cursor) {
    int i = blockIdx.x * blockDim.x + threadIdx.x;
    if (i >= NN) return;
    int inc = partial[i] + blocksum[i / SB];
    rowptr[i + 1] = inc;
    cursor[i] = inc - deg[i];
    if (i == 0) rowptr[0] = 0;
}

__global__ void scatter_csr(const int* __restrict__ src, const int* __restrict__ dst,
                            int* __restrict__ cursor, int* __restrict__ csr_src) {
    int e = blockIdx.x * blockDim.x + threadIdx.x;
    if (e >= NE) return;
    int d = dst[e];
    int pos = atomicAdd(&cursor[d], 1);
    csr_src[pos] = src[e];
}

// ---------------- fused GATv2: 1 wave per node, 4 slots x 16 lanes ----------------
__global__ __launch_bounds__(256) void gat_fused(
    const unsigned short* __restrict__ h, const int* __restrict__ rowptr,
    const int* __restrict__ csr_src, const float* __restrict__ att,
    const float* __restrict__ bias, const float* __restrict__ skip,
    void* __restrict__ out, int last) {
    int wid = threadIdx.x >> 6;
    int n = blockIdx.x * 4 + wid;
    if (n >= NN) return;
    int lane = threadIdx.x & 63;
    int slot = lane >> 4;
    int t = lane & 15;

    ushort8v hdv = *(const ushort8v*)(h + (size_t)n * HC + t * 8);
    float hd[8], av[8];
    #pragma unroll
    for (int c = 0; c < 8; ++c) hd[c] = bf2f(hdv[c]);
    float4 av0 = ((const float4*)att)[t * 2];
    float4 av1 = ((const float4*)att)[t * 2 + 1];
    av[0] = av0.x; av[1] = av0.y; av[2] = av0.z; av[3] = av0.w;
    av[4] = av1.x; av[5] = av1.y; av[6] = av1.z; av[7] = av1.w;

    int beg = rowptr[n], end = rowptr[n + 1];
    float l = 0.f;
    float acc[8] = {};

    int i0 = beg + slot;
    ushort8v b0 = 0, b1 = 0;
    if (i0 < end)     b0 = *(const ushort8v*)(h + (size_t)csr_src[i0] * HC + t * 8);
    if (i0 + 4 < end) b1 = *(const ushort8v*)(h + (size_t)csr_src[i0 + 4] * HC + t * 8);

    for (int i = i0; i < end; i += 4) {
        float hs[8];
        #pragma unroll
        for (int c = 0; c < 8; ++c) hs[c] = bf2f(b0[c]);
        b0 = b1;
        if (i + 8 < end)
            b1 = *(const ushort8v*)(h + (size_t)csr_src[i + 8] * HC + t * 8);
        float part = 0.f;
        #pragma unroll
        for (int c = 0; c < 8; ++c) {
            float v = hs[c] + hd[c];
            float lr = fmaxf(v, 0.f) + NEG_SLOPE * fminf(v, 0.f);
            part += lr * av[c];
        }
        part += __shfl_xor(part, 1, 64);   // reduce over 4-lane head group
        part += __shfl_xor(part, 2, 64);
        float p = __expf(part);
        #pragma unroll
        for (int c = 0; c < 8; ++c) acc[c] += p * hs[c];
        l += p;
    }

    // merge the 4 slots (lane quadrants) via cross-lane xor sums
    l += __shfl_xor(l, 16, 64);
    l += __shfl_xor(l, 32, 64);
    #pragma unroll
    for (int c = 0; c < 8; ++c) {
        acc[c] += __shfl_xor(acc[c], 16, 64);
        acc[c] += __shfl_xor(acc[c], 32, 64);
    }

    float inv = 1.f / fmaxf(l, 1e-16f);
    float o[8];
    #pragma unroll
    for (int c = 0; c < 8; ++c) o[c] = acc[c] * inv;

    if (!last) {
        if (lane < 16) {
            float4 bv0 = ((const float4*)bias)[t * 2];
            float4 bv1 = ((const float4*)bias)[t * 2 + 1];
            float4 sk0 = ((const float4*)(skip + (size_t)n * HC))[t * 2];
            float4 sk1 = ((const float4*)(skip + (size_t)n * HC))[t * 2 + 1];
            float bb[8] = {bv0.x, bv0.y, bv0.z, bv0.w, bv1.x, bv1.y, bv1.z, bv1.w};
            float sk[8] = {sk0.x, sk0.y, sk0.z, sk0.w, sk1.x, sk1.y, sk1.z, sk1.w};
            ushort8v ov;
            #pragma unroll
            for (int c = 0; c < 8; ++c) {
                float r = o[c] + bb[c] + sk[c];
                r = r > 0.f ? r : (__expf(r) - 1.f);   // ELU
                ov[c] = f2bf(r);
            }
            *(ushort8v*)((unsigned short*)out + (size_t)n * HC + t * 8) = ov;
        }
    } else {
        float r4[8], r8[8], r12[8];
        #pragma unroll
        for (int c = 0; c < 8; ++c) {
            r4[c]  = __shfl_down(o[c], 4, 64);
            r8[c]  = __shfl_down(o[c], 8, 64);
            r12[c] = __shfl_down(o[c], 12, 64);
        }
        if (lane < 4) {
            float* op = (float*)out + (size_t)n * NC + lane * 8;
            float rr[8];
            #pragma unroll
            for (int c = 0; c < 8; ++c) {
                rr[c] = 0.25f * (o[c] + r4[c] + r8[c] + r12[c])
                      + bias[lane * 8 + c] + skip[(size_t)n * NC + lane * 8 + c];
            }
            *(float4*)op = (float4){rr[0], rr[1], rr[2], rr[3]};
            *(float4*)(op + 4) = (float4){rr[4], rr[5], rr[6], rr[7]};
        }
    }
}

extern "C" void kernel_launch(void* const* d_in, const int* in_sizes, int n_in,
                              void* d_out, int out_size, void* d_ws, size_t ws_size,
                              hipStream_t stream) {
    const float* x0 = (const float*)d_in[0];
    const int* ei = (const int*)d_in[1];
    const int* src = ei;
    const int* dst = ei + NE;

    unsigned short* xbuf = (unsigned short*)d_ws;            // NN*HC bf16
    unsigned short* h    = xbuf + (size_t)NN * HC;           // NN*HC bf16
    float* skip  = (float*)(h + (size_t)NN * HC);            // NN*HC fp32
    int* deg     = (int*)(skip + (size_t)NN * HC);           // NN
    int* rowptr  = deg + NN;                                 // NN+1
    int* cursor  = rowptr + NN + 1;                          // NN
    int* partial = cursor + NN;                              // NN
    int* blocksum = partial + NN;                            // SNB
    // 16B-aligned Wt area (bf16, [col][k] layout, k-stride 128)
    uintptr_t p = (uintptr_t)(blocksum + SNB);
    p = (p + 15) & ~(uintptr_t)15;
    unsigned short* wt = (unsigned short*)p;
    unsigned short* wtW[3]  = {wt, wt + 32768, wt + 65536};          // 128x128 each
    unsigned short* wtS[3]  = {wt + 16384, wt + 49152, wt + 81920};  // l2 skip = 32x128
    int* csr_src = (int*)(wt + 86016);                       // NE

    // ---- weight pre-transpose (6 matrices, once) ----
    for (int l = 0; l < 3; ++l) {
        const float* W     = (const float*)d_in[2 + 6 * l + 0];
        const float* skipW = (const float*)d_in[2 + 6 * l + 4];
        w_transpose<<<128, 128, 0, stream>>>(W, wtW[l], 128);
        w_transpose<<<(l < 2) ? 128 : 32, 128, 0, stream>>>(skipW, wtS[l], (l < 2) ? 128 : 32);
    }

    // ---- CSR build (once; reused by all 3 layers) ----
    hipMemsetAsync(deg, 0, (size_t)NN * sizeof(int), stream);
    hist_deg<<<(NE + 255) / 256, 256, 0, stream>>>(dst, deg);
    scan1<<<SNB, SB, 0, stream>>>(deg, partial, blocksum);
    scan2<<<1, 128, 0, stream>>>(blocksum);
    scan3<<<(NN + 255) / 256, 256, 0, stream>>>(deg, partial, blocksum, rowptr, cursor);
    scatter_csr<<<(NE + 255) / 256, 256, 0, stream>>>(src, dst, cursor, csr_src);

    const int GLF = (NN + 127) / 128;   // 391 blocks x 4 waves x 32 rows
    const int GGAT = (NN + 3) / 4;

    for (int l = 0; l < 3; ++l) {
        const float* linb  = (const float*)d_in[2 + 6 * l + 1];
        const float* att   = (const float*)d_in[2 + 6 * l + 2];
        const float* bias  = (const float*)d_in[2 + 6 * l + 3];
        const float* skipb = (const float*)d_in[2 + 6 * l + 5];

        if (l == 0) {
            gemm_dual_lf<float><<<dim3(GLF, 2), 256, 0, stream>>>(
                x0, wtW[0], linb, h, wtS[0], skipb, skip);
        } else if (l == 1) {
            gemm_dual_lf<unsigned short><<<dim3(GLF, 2), 256, 0, stream>>>(
                xbuf, wtW[1], linb, h, wtS[1], skipb, skip);
        } else {
            gemm_one_lf<unsigned short, 128, 1><<<GLF, 256, 0, stream>>>(xbuf, wtW[2], linb, h);
            gemm_one_lf<unsigned short, 32, 0><<<GLF, 256, 0, stream>>>(xbuf, wtS[2], skipb, skip);
        }

        void* outp = (l < 2) ? (void*)xbuf : (void*)d_out;
        gat_fused<<<GGAT, 256, 0, stream>>>(h, rowptr, csr_src, att, bias, skip, outp, l == 2 ? 1 : 0);
    }
}

// Round 12
// 369.400 us; speedup vs baseline: 1.0909x; 1.0909x over previous
//
#include <hip/hip_runtime.h>
#include <hip/hip_bf16.h>

#define NN 50000
#define NE 600000
#define IN_DIM 128
#define HC 128      // H*C
#define NH 4
#define NC 32
#define NEG_SLOPE 0.2f

#define SB 512
#define SNB ((NN + SB - 1) / SB)   // 98 scan blocks

typedef __attribute__((ext_vector_type(8))) short short8;
typedef __attribute__((ext_vector_type(4))) float floatx4;
typedef __attribute__((ext_vector_type(8))) unsigned short ushort8v;

__device__ __forceinline__ float bf2f(unsigned short u) {
    return __uint_as_float(((unsigned)u) << 16);
}
__device__ __forceinline__ unsigned short f2bf(float f) {
    unsigned u = __float_as_uint(f);
    unsigned r = (u + 0x7FFFu + ((u >> 16) & 1u)) >> 16;   // RNE
    return (unsigned short)r;
}

// ---------------- fused weight pre-transpose: one launch for all 6 matrices ----------------
// Wt[n][k] = bf16(W[k][n]); 672 blocks x 128 threads.
__global__ void w_transpose_all(const float* __restrict__ W0, const float* __restrict__ S0,
                                const float* __restrict__ W1, const float* __restrict__ S1,
                                const float* __restrict__ W2, const float* __restrict__ S2,
                                unsigned short* __restrict__ wt) {
    int b = blockIdx.x, k = threadIdx.x;
    const float* W; unsigned short* out; int OD; int n;
    if (b < 128)      { W = W0; out = wt;          OD = 128; n = b; }
    else if (b < 256) { W = S0; out = wt + 16384;  OD = 128; n = b - 128; }
    else if (b < 384) { W = W1; out = wt + 32768;  OD = 128; n = b - 256; }
    else if (b < 512) { W = S1; out = wt + 49152;  OD = 128; n = b - 384; }
    else if (b < 640) { W = W2; out = wt + 65536;  OD = 128; n = b - 512; }
    else              { W = S2; out = wt + 81920;  OD = 32;  n = b - 640; }
    out[n * 128 + k] = f2bf(W[(size_t)k * OD + n]);
}

// ============ LDS-free MFMA GEMM, transposed-D epilogue ============
// mfma(A=Wt frag, B=x frag): D[m=out-channel][n=node] -> lane holds node
// (l16-indexed) with 4 CONTIGUOUS channels per (tc,quad) -> wide stores.
template<typename AT, int OD, int OBF>
__device__ __forceinline__ void gemm_wave(
    const AT* __restrict__ x, const unsigned short* __restrict__ Wt,
    const float* __restrict__ b, void* __restrict__ yv, int n0, int lane) {
    int quad = lane >> 4, l16 = lane & 15;
    floatx4 acc[2][OD / 16];
    #pragma unroll
    for (int i = 0; i < 2; ++i)
        #pragma unroll
        for (int j = 0; j < OD / 16; ++j) acc[i][j] = (floatx4){0.f, 0.f, 0.f, 0.f};

    int r0 = n0 + l16;      if (r0 >= NN) r0 = NN - 1;
    int r1 = n0 + 16 + l16; if (r1 >= NN) r1 = NN - 1;

    #pragma unroll
    for (int ks = 0; ks < 4; ++ks) {
        int kb = ks * 32 + quad * 8;
        short8 xb0, xb1;   // x fragments = B operand (B[k][n], n=l16=node)
        if constexpr (sizeof(AT) == 4) {
            const float* xr = (const float*)x;
            float4 v0 = *(const float4*)&xr[(size_t)r0 * IN_DIM + kb];
            float4 v1 = *(const float4*)&xr[(size_t)r0 * IN_DIM + kb + 4];
            float4 u0 = *(const float4*)&xr[(size_t)r1 * IN_DIM + kb];
            float4 u1 = *(const float4*)&xr[(size_t)r1 * IN_DIM + kb + 4];
            xb0 = (short8){(short)f2bf(v0.x), (short)f2bf(v0.y), (short)f2bf(v0.z), (short)f2bf(v0.w),
                           (short)f2bf(v1.x), (short)f2bf(v1.y), (short)f2bf(v1.z), (short)f2bf(v1.w)};
            xb1 = (short8){(short)f2bf(u0.x), (short)f2bf(u0.y), (short)f2bf(u0.z), (short)f2bf(u0.w),
                           (short)f2bf(u1.x), (short)f2bf(u1.y), (short)f2bf(u1.z), (short)f2bf(u1.w)};
        } else {
            xb0 = *(const short8*)&((const unsigned short*)x)[(size_t)r0 * IN_DIM + kb];
            xb1 = *(const short8*)&((const unsigned short*)x)[(size_t)r1 * IN_DIM + kb];
        }
        #pragma unroll
        for (int tc = 0; tc < OD / 16; ++tc) {
            // A-frag: A[m=l16=out-col][k=quad*8+j] from Wt row (tc*16+l16)
            short8 af = *(const short8*)&Wt[(size_t)(tc * 16 + l16) * 128 + kb];
            acc[0][tc] = __builtin_amdgcn_mfma_f32_16x16x32_bf16(af, xb0, acc[0][tc], 0, 0, 0);
            acc[1][tc] = __builtin_amdgcn_mfma_f32_16x16x32_bf16(af, xb1, acc[1][tc], 0, 0, 0);
        }
    }

    // epilogue: D[m][n] -> m = tc*16 + quad*4 + reg (channel), n = l16 (node)
    #pragma unroll
    for (int tc = 0; tc < OD / 16; ++tc) {
        int cbase = tc * 16 + quad * 4;
        float4 bv = *(const float4*)&b[cbase];
        #pragma unroll
        for (int i = 0; i < 2; ++i) {
            int node = n0 + i * 16 + l16;
            if (node < NN) {
                float v0 = acc[i][tc][0] + bv.x;
                float v1 = acc[i][tc][1] + bv.y;
                float v2 = acc[i][tc][2] + bv.z;
                float v3 = acc[i][tc][3] + bv.w;
                if constexpr (OBF) {
                    ushort4 pk = {f2bf(v0), f2bf(v1), f2bf(v2), f2bf(v3)};
                    *(ushort4*)&((unsigned short*)yv)[(size_t)node * OD + cbase] = pk;
                } else {
                    *(float4*)&((float*)yv)[(size_t)node * OD + cbase] = (float4){v0, v1, v2, v3};
                }
            }
        }
    }
}

// dual GEMM (l<2): grid.y==0 -> h (bf16), grid.y==1 -> skip (fp32), both OD=128
template<typename AT>
__global__ __launch_bounds__(256) void gemm_dual_lf(
    const AT* __restrict__ x,
    const unsigned short* __restrict__ Wta, const float* __restrict__ ba, unsigned short* __restrict__ ya,
    const unsigned short* __restrict__ Wtb, const float* __restrict__ bb, float* __restrict__ yb) {
    int wid = threadIdx.x >> 6, lane = threadIdx.x & 63;
    int n0 = (blockIdx.x * 4 + wid) * 32;
    if (n0 >= NN) return;
    if (blockIdx.y == 0) gemm_wave<AT, 128, 1>(x, Wta, ba, (void*)ya, n0, lane);
    else                 gemm_wave<AT, 128, 0>(x, Wtb, bb, (void*)yb, n0, lane);
}

// l=2: grid.y==0 -> h (128, bf16), grid.y==1 -> skip (32, fp32)
__global__ __launch_bounds__(256) void gemm_dual_l2(
    const unsigned short* __restrict__ x,
    const unsigned short* __restrict__ Wta, const float* __restrict__ ba, unsigned short* __restrict__ ya,
    const unsigned short* __restrict__ Wtb, const float* __restrict__ bb, float* __restrict__ yb) {
    int wid = threadIdx.x >> 6, lane = threadIdx.x & 63;
    int n0 = (blockIdx.x * 4 + wid) * 32;
    if (n0 >= NN) return;
    if (blockIdx.y == 0) gemm_wave<unsigned short, 128, 1>(x, Wta, ba, (void*)ya, n0, lane);
    else                 gemm_wave<unsigned short, 32, 0>(x, Wtb, bb, (void*)yb, n0, lane);
}

// ---------------- CSR build ----------------
__global__ void hist_deg(const int* __restrict__ dst, int* __restrict__ deg) {
    int e = blockIdx.x * blockDim.x + threadIdx.x;
    if (e < NE) atomicAdd(&deg[dst[e]], 1);
}

__global__ __launch_bounds__(SB) void scan1(const int* __restrict__ deg,
                                            int* __restrict__ partial,
                                            int* __restrict__ blocksum) {
    __shared__ int sh[SB];
    int b = blockIdx.x, t = threadIdx.x;
    int i = b * SB + t;
    int d = (i < NN) ? deg[i] : 0;
    sh[t] = d;
    __syncthreads();
    #pragma unroll
    for (int off = 1; off < SB; off <<= 1) {
        int v = (t >= off) ? sh[t - off] : 0;
        __syncthreads();
        sh[t] += v;
        __syncthreads();
    }
    if (i < NN) partial[i] = sh[t];
    if (t == SB - 1) blocksum[b] = sh[t];
}

__global__ __launch_bounds__(128) void scan2(int* __restrict__ blocksum) {
    __shared__ int sh[128];
    int t = threadIdx.x;
    int v = (t < SNB) ? blocksum[t] : 0;
    sh[t] = v;
    __syncthreads();
    #pragma unroll
    for (int off = 1; off < 128; off <<= 1) {
        int u = (t >= off) ? sh[t - off] : 0;
        __syncthreads();
        sh[t] += u;
        __syncthreads();
    }
    if (t < SNB) blocksum[t] = sh[t] - v;   // exclusive prefix
}

__global__ void scan3(const int* __restrict__ deg, const int* __restrict__ partial,
                      const int* __restrict__ blocksum, int* __restrict__ rowptr,
                      int* __restrict__ cursor) {
    int i = blockIdx.x * blockDim.x + threadIdx.x;
    if (i >= NN) return;
    int inc = partial[i] + blocksum[i / SB];
    rowptr[i + 1] = inc;
    cursor[i] = inc - deg[i];
    if (i == 0) rowptr[0] = 0;
}

__global__ void scatter_csr(const int* __restrict__ src, const int* __restrict__ dst,
                            int* __restrict__ cursor, int* __restrict__ csr_src) {
    int e = blockIdx.x * blockDim.x + threadIdx.x;
    if (e >= NE) return;
    int d = dst[e];
    int pos = atomicAdd(&cursor[d], 1);
    csr_src[pos] = src[e];
}

// ---------------- fused GATv2: 1 wave per node, 4 slots x 16 lanes ----------------
__global__ __launch_bounds__(256) void gat_fused(
    const unsigned short* __restrict__ h, const int* __restrict__ rowptr,
    const int* __restrict__ csr_src, const float* __restrict__ att,
    const float* __restrict__ bias, const float* __restrict__ skip,
    void* __restrict__ out, int last) {
    int wid = threadIdx.x >> 6;
    int n = blockIdx.x * 4 + wid;
    if (n >= NN) return;
    int lane = threadIdx.x & 63;
    int slot = lane >> 4;
    int t = lane & 15;

    ushort8v hdv = *(const ushort8v*)(h + (size_t)n * HC + t * 8);
    float hd[8], av[8];
    #pragma unroll
    for (int c = 0; c < 8; ++c) hd[c] = bf2f(hdv[c]);
    float4 av0 = ((const float4*)att)[t * 2];
    float4 av1 = ((const float4*)att)[t * 2 + 1];
    av[0] = av0.x; av[1] = av0.y; av[2] = av0.z; av[3] = av0.w;
    av[4] = av1.x; av[5] = av1.y; av[6] = av1.z; av[7] = av1.w;

    int beg = rowptr[n], end = rowptr[n + 1];
    float l = 0.f;
    float acc[8] = {};

    int i0 = beg + slot;
    ushort8v b0 = 0, b1 = 0;
    if (i0 < end)     b0 = *(const ushort8v*)(h + (size_t)csr_src[i0] * HC + t * 8);
    if (i0 + 4 < end) b1 = *(const ushort8v*)(h + (size_t)csr_src[i0 + 4] * HC + t * 8);

    for (int i = i0; i < end; i += 4) {
        float hs[8];
        #pragma unroll
        for (int c = 0; c < 8; ++c) hs[c] = bf2f(b0[c]);
        b0 = b1;
        if (i + 8 < end)
            b1 = *(const ushort8v*)(h + (size_t)csr_src[i + 8] * HC + t * 8);
        float part = 0.f;
        #pragma unroll
        for (int c = 0; c < 8; ++c) {
            float v = hs[c] + hd[c];
            float lr = fmaxf(v, 0.f) + NEG_SLOPE * fminf(v, 0.f);
            part += lr * av[c];
        }
        part += __shfl_xor(part, 1, 64);   // reduce over 4-lane head group
        part += __shfl_xor(part, 2, 64);
        float p = __expf(part);
        #pragma unroll
        for (int c = 0; c < 8; ++c) acc[c] += p * hs[c];
        l += p;
    }

    // merge the 4 slots (lane quadrants) via cross-lane xor sums
    l += __shfl_xor(l, 16, 64);
    l += __shfl_xor(l, 32, 64);
    #pragma unroll
    for (int c = 0; c < 8; ++c) {
        acc[c] += __shfl_xor(acc[c], 16, 64);
        acc[c] += __shfl_xor(acc[c], 32, 64);
    }

    float inv = 1.f / fmaxf(l, 1e-16f);
    float o[8];
    #pragma unroll
    for (int c = 0; c < 8; ++c) o[c] = acc[c] * inv;

    if (!last) {
        if (lane < 16) {
            float4 bv0 = ((const float4*)bias)[t * 2];
            float4 bv1 = ((const float4*)bias)[t * 2 + 1];
            float4 sk0 = ((const float4*)(skip + (size_t)n * HC))[t * 2];
            float4 sk1 = ((const float4*)(skip + (size_t)n * HC))[t * 2 + 1];
            float bb[8] = {bv0.x, bv0.y, bv0.z, bv0.w, bv1.x, bv1.y, bv1.z, bv1.w};
            float sk[8] = {sk0.x, sk0.y, sk0.z, sk0.w, sk1.x, sk1.y, sk1.z, sk1.w};
            ushort8v ov;
            #pragma unroll
            for (int c = 0; c < 8; ++c) {
                float r = o[c] + bb[c] + sk[c];
                r = r > 0.f ? r : (__expf(r) - 1.f);   // ELU
                ov[c] = f2bf(r);
            }
            *(ushort8v*)((unsigned short*)out + (size_t)n * HC + t * 8) = ov;
        }
    } else {
        float r4[8], r8[8], r12[8];
        #pragma unroll
        for (int c = 0; c < 8; ++c) {
            r4[c]  = __shfl_down(o[c], 4, 64);
            r8[c]  = __shfl_down(o[c], 8, 64);
            r12[c] = __shfl_down(o[c], 12, 64);
        }
        if (lane < 4) {
            float* op = (float*)out + (size_t)n * NC + lane * 8;
            float rr[8];
            #pragma unroll
            for (int c = 0; c < 8; ++c) {
                rr[c] = 0.25f * (o[c] + r4[c] + r8[c] + r12[c])
                      + bias[lane * 8 + c] + skip[(size_t)n * NC + lane * 8 + c];
            }
            *(float4*)op = (float4){rr[0], rr[1], rr[2], rr[3]};
            *(float4*)(op + 4) = (float4){rr[4], rr[5], rr[6], rr[7]};
        }
    }
}

extern "C" void kernel_launch(void* const* d_in, const int* in_sizes, int n_in,
                              void* d_out, int out_size, void* d_ws, size_t ws_size,
                              hipStream_t stream) {
    const float* x0 = (const float*)d_in[0];
    const int* ei = (const int*)d_in[1];
    const int* src = ei;
    const int* dst = ei + NE;

    unsigned short* xbuf = (unsigned short*)d_ws;            // NN*HC bf16
    unsigned short* h    = xbuf + (size_t)NN * HC;           // NN*HC bf16
    float* skip  = (float*)(h + (size_t)NN * HC);            // NN*HC fp32
    int* deg     = (int*)(skip + (size_t)NN * HC);           // NN
    int* rowptr  = deg + NN;                                 // NN+1
    int* cursor  = rowptr + NN + 1;                          // NN
    int* partial = cursor + NN;                              // NN
    int* blocksum = partial + NN;                            // SNB
    // 16B-aligned Wt area (bf16, [col][k] layout, k-stride 128)
    uintptr_t p = (uintptr_t)(blocksum + SNB);
    p = (p + 15) & ~(uintptr_t)15;
    unsigned short* wt = (unsigned short*)p;
    unsigned short* wtW[3]  = {wt, wt + 32768, wt + 65536};          // 128x128 each
    unsigned short* wtS[3]  = {wt + 16384, wt + 49152, wt + 81920};  // l2 skip = 32x128
    int* csr_src = (int*)(wt + 86016);                       // NE

    // ---- weight pre-transpose: ONE launch for all 6 matrices ----
    w_transpose_all<<<672, 128, 0, stream>>>(
        (const float*)d_in[2], (const float*)d_in[6],
        (const float*)d_in[8], (const float*)d_in[12],
        (const float*)d_in[14], (const float*)d_in[18], wt);

    // ---- CSR build (once; reused by all 3 layers) ----
    hipMemsetAsync(deg, 0, (size_t)NN * sizeof(int), stream);
    hist_deg<<<(NE + 255) / 256, 256, 0, stream>>>(dst, deg);
    scan1<<<SNB, SB, 0, stream>>>(deg, partial, blocksum);
    scan2<<<1, 128, 0, stream>>>(blocksum);
    scan3<<<(NN + 255) / 256, 256, 0, stream>>>(deg, partial, blocksum, rowptr, cursor);
    scatter_csr<<<(NE + 255) / 256, 256, 0, stream>>>(src, dst, cursor, csr_src);

    const int GLF = (NN + 127) / 128;   // 391 blocks x 4 waves x 32 rows
    const int GGAT = (NN + 3) / 4;

    for (int l = 0; l < 3; ++l) {
        const float* linb  = (const float*)d_in[2 + 6 * l + 1];
        const float* att   = (const float*)d_in[2 + 6 * l + 2];
        const float* bias  = (const float*)d_in[2 + 6 * l + 3];
        const float* skipb = (const float*)d_in[2 + 6 * l + 5];

        if (l == 0) {
            gemm_dual_lf<float><<<dim3(GLF, 2), 256, 0, stream>>>(
                x0, wtW[0], linb, h, wtS[0], skipb, skip);
        } else if (l == 1) {
            gemm_dual_lf<unsigned short><<<dim3(GLF, 2), 256, 0, stream>>>(
                xbuf, wtW[1], linb, h, wtS[1], skipb, skip);
        } else {
            gemm_dual_l2<<<dim3(GLF, 2), 256, 0, stream>>>(
                xbuf, wtW[2], linb, h, wtS[2], skipb, skip);
        }

        void* outp = (l < 2) ? (void*)xbuf : (void*)d_out;
        gat_fused<<<GGAT, 256, 0, stream>>>(h, rowptr, csr_src, att, bias, skip, outp, l == 2 ? 1 : 0);
    }
}